// Round 14
// baseline (1499.921 us; speedup 1.0000x reference)
//
#include <hip/hip_runtime.h>
#include <math.h>

// GraphEncoder v20 = v19 (1444us, PASSED) + two independent changes:
//  (a) phase ssum via pad column: fac writes P[50]=1.0; the gather's 13th
//      float4 (elements 48-51, already fetched) then accumulates ev*1 into
//      a4.z of lane sub4==12 -> after the existing 2-step a4 reduce, lane
//      12's a4.z IS the row's ssum. Deletes the 6-step serial shfl_xor
//      reduce + per-chunk ssum add; adds one __shfl. Arithmetic-only:
//      cannot fault. (Invalid edges carry ev=0 -> sum equivalent.)
//  (b) place: __builtin_nontemporal_store for the scattered u16 (v15
//      signature: WRITE_SIZE 200MB for 5.2MB colind = full-line RFO per
//      u16). Never isolated in v17/v18 (infra crashes); a crash this round
//      cleanly implicates NT since (a) cannot fault.

#define KF 2
#define DK 25
#define DD 50
#define PS 52   // padded P/z row stride: 208 B = 13 float4
#define ITERS 4
#define WPB 4

static __device__ __forceinline__ float leakyf(float x) { return x > 0.f ? x : 0.2f * x; }

static __device__ __forceinline__ float fast_tanhf(float x) {
    float e = __expf(2.f * x);
    return 1.f - 2.f * __builtin_amdgcn_rcpf(e + 1.f);
}

// at[e] is [2][50]: factor k at a+k*50; 0..24 row-side, 25..49 col-side.
static __device__ __forceinline__ float2 score_row50(const float* p, const float* a) {
    float s0 = 0.f, s1 = 0.f;
    #pragma unroll
    for (int f = 0; f < DK; ++f) {
        s0 = fmaf(p[f],      a[f],      s0);
        s1 = fmaf(p[DK + f], a[50 + f], s1);
    }
    return make_float2(s0, s1);
}
static __device__ __forceinline__ float2 score_col50(const float* p, const float* a) {
    float s0 = 0.f, s1 = 0.f;
    #pragma unroll
    for (int f = 0; f < DK; ++f) {
        s0 = fmaf(p[f],      a[25 + f], s0);
        s1 = fmaf(p[DK + f], a[75 + f], s1);
    }
    return make_float2(s0, s1);
}

// ---------------- fac ----------------
struct FacArgs { const float* emb[8]; float* P[8]; const float* Wtk; int base[9]; };

__global__ void fac_kernel(FacArgs A) {
    int g = blockIdx.x * blockDim.x + threadIdx.x;
    if (g >= A.base[8]) return;
    int ty = 0;
    while (g >= A.base[ty + 1]) ++ty;
    int node = g - A.base[ty];
    const float* er = A.emb[ty] + (size_t)node * DD;
    const float* Wt = A.Wtk + (size_t)ty * KF * DD * DK;
    float x[DD];
    #pragma unroll
    for (int d = 0; d < DD; ++d) x[d] = er[d];
    float out[DD];
    #pragma unroll
    for (int k = 0; k < KF; ++k) {
        const float* Wk = Wt + k * DD * DK;
        float nrm = 0.f;
        for (int f = 0; f < DK; ++f) {
            float acc = 0.f;
            for (int d = 0; d < DD; ++d) acc = fmaf(x[d], Wk[d * DK + f], acc);
            acc = leakyf(acc);
            out[k * DK + f] = acc;
            nrm = fmaf(acc, acc, nrm);
        }
        float inv = 1.f / fmaxf(sqrtf(nrm), 1e-12f);
        for (int f = 0; f < DK; ++f) out[k * DK + f] *= inv;
    }
    float* Pr = A.P[ty] + (size_t)node * PS;
    #pragma unroll
    for (int j = 0; j < DD; ++j) Pr[j] = out[j];
    Pr[50] = 1.f;   // ssum pad column: gather accumulates ev*1 into a4.z
    Pr[51] = 0.f;
}

// ---------------- flat CSR build (single atomic pass) ----------------
struct EdgeArgs {
    const int* rows[8]; const int* cols[8];
    int* cnt;                  // [totalRows+1] counts -> exclusive starts
    unsigned* rank;            // [totE] within-row rank
    unsigned short* colind;    // [totE] flat
    int ebase[9];
    int rowbase[8];
};

__global__ void rank_kernel(EdgeArgs A) {
    int g = blockIdx.x * blockDim.x + threadIdx.x;
    if (g >= A.ebase[8]) return;
    int rel = 0;
    while (g >= A.ebase[rel + 1]) ++rel;
    int e = g - A.ebase[rel];
    A.rank[g] = (unsigned)atomicAdd(&A.cnt[A.rowbase[rel] + A.rows[rel][e]], 1);
}

// 3-kernel hierarchical exclusive scan over cnt[0..n)
__global__ __launch_bounds__(1024) void scan_part_kernel(int* a, int n, int* bsum) {
    __shared__ int lds[1024];
    int tid = threadIdx.x;
    int i = blockIdx.x * 1024 + tid;
    int v = (i < n) ? a[i] : 0;
    lds[tid] = v;
    __syncthreads();
    int x = v;
    for (int off = 1; off < 1024; off <<= 1) {
        int y = (tid >= off) ? lds[tid - off] : 0;
        __syncthreads();
        x += y;
        lds[tid] = x;
        __syncthreads();
    }
    if (i < n) a[i] = x - v;              // exclusive within chunk
    if (tid == 1023) bsum[blockIdx.x] = x; // chunk total
}

__global__ __launch_bounds__(1024) void scan_bsum_kernel(int* bsum, int nb) {
    __shared__ int lds[1024];
    int tid = threadIdx.x;
    int v = (tid < nb) ? bsum[tid] : 0;
    lds[tid] = v;
    __syncthreads();
    int x = v;
    for (int off = 1; off < 1024; off <<= 1) {
        int y = (tid >= off) ? lds[tid - off] : 0;
        __syncthreads();
        x += y;
        lds[tid] = x;
        __syncthreads();
    }
    if (tid < nb) bsum[tid] = x - v;      // exclusive chunk offsets
}

__global__ __launch_bounds__(1024) void add_off_kernel(int* a, int n, const int* bsum) {
    int i = blockIdx.x * 1024 + threadIdx.x;
    if (i < n) a[i] += bsum[blockIdx.x];
}

// place: no atomics; p = start[grow] + rank[e]; NT store avoids full-line
// RFO/writeback for the scattered u16.
__global__ void place_kernel(EdgeArgs A) {
    int g = blockIdx.x * blockDim.x + threadIdx.x;
    if (g >= A.ebase[8]) return;
    int rel = 0;
    while (g >= A.ebase[rel + 1]) ++rel;
    int e = g - A.ebase[rel];
    int p = A.cnt[A.rowbase[rel] + A.rows[rel][e]] + (int)A.rank[g];
    __builtin_nontemporal_store((unsigned short)A.cols[rel][e], &A.colind[p]);
}

// ---------------- sb init for static relations 2..7 ----------------
struct SbArgs { const float* Pb[6]; const float* at[6]; float2* sb[6]; int base[7]; };

__global__ void sb_kernel(SbArgs A) {
    int g = blockIdx.x * blockDim.x + threadIdx.x;
    if (g >= A.base[6]) return;
    int rel = 0;
    while (g >= A.base[rel + 1]) ++rel;
    int c = g - A.base[rel];
    const float* p = A.Pb[rel] + (size_t)c * PS;
    A.sb[rel][c] = score_col50(p, A.at[rel]);
}

// ---------------- score01: INITIAL sa (all rels) + sb0/sb1 (after fac) ----------------
struct ScoreArgs {
    const float* P0; const float* P1;
    const float* at;
    float2* sa[8]; float2* sb0; float2* sb1;
    int n0, n1;
};

__global__ void score01_kernel(ScoreArgs A) {
    int g = blockIdx.x * blockDim.x + threadIdx.x;
    if (g >= A.n0 + A.n1) return;
    if (g < A.n0) {
        const float* p = A.P0 + (size_t)g * PS;
        float pr[DD];
        #pragma unroll
        for (int j = 0; j < DD; ++j) pr[j] = p[j];
        A.sa[0][g] = score_row50(pr, A.at + 0);
        A.sb1[g]   = score_col50(pr, A.at + 100);
    } else {
        int node = g - A.n0;
        const float* p = A.P1 + (size_t)node * PS;
        float pr[DD];
        #pragma unroll
        for (int j = 0; j < DD; ++j) pr[j] = p[j];
        #pragma unroll
        for (int e = 1; e < 8; ++e) A.sa[e][node] = score_row50(pr, A.at + e * 100);
        A.sb0[node] = score_col50(pr, A.at + 0);
    }
}

// ---------------- fused phase (gather + LDS epilogue; ssum via pad) ----------------
struct PhaseArgs {
    const int* rowptr;               // [totalRows+1] exclusive starts (flat)
    const unsigned short* colind;    // flat
    const float* Pb[8];
    const float* q[8];
    const float2* sa[8]; const float2* sb[8];
    float* z[8]; float* r[8];
    const float* W;
    int rowbase[9];
};

__global__ __launch_bounds__(WPB * 64) void phase_kernel(PhaseArgs A, int totalRows) {
    __shared__ float Wsh[DK * DK];
    __shared__ float zsh[WPB][DD];
    for (int i = threadIdx.x; i < DK * DK; i += WPB * 64) Wsh[i] = A.W[i];
    __syncthreads();

    int wslot = threadIdx.x >> 6;
    int wave = blockIdx.x * WPB + wslot;
    int lane = threadIdx.x & 63;
    if (wave >= totalRows) return;
    int rel = 0;
    while (wave >= A.rowbase[rel + 1]) ++rel;
    int u = wave - A.rowbase[rel];

    const unsigned short* colind = A.colind;
    const char* Pb = (const char*)A.Pb[rel];
    const float* qv = A.q[rel];
    const float2* sb = A.sb[rel];
    float2 h = A.sa[rel][u];
    int beg = A.rowptr[wave];
    int end = A.rowptr[wave + 1];

    bool act = lane < DD;
    int grp4 = lane >> 4, sub4 = lane & 15;
    bool ld = sub4 < 13;   // P row is 13 float4; element 50 is the ssum pad
    float4 a4 = make_float4(0.f, 0.f, 0.f, 0.f);

    for (int base = beg; base < end; base += 64) {
        int idx = base + lane;
        bool vld = idx < end;
        int cb = vld ? (int)colind[idx] : 0;
        unsigned ob = (unsigned)cb * (unsigned)(PS * 4);   // byte offset, 64-wide
        float evl = 0.f;
        if (vld) {
            float2 sc = sb[cb];
            evl = __expf(0.5f * (fmaxf(h.x + sc.x, 0.f) + fmaxf(h.y + sc.y, 0.f)));
        }
        int nb = min(64, end - base);
        #pragma unroll 4
        for (int t = 0; t < nb; t += 4) {
            int srcl = t + grp4;
            unsigned o4 = __shfl(ob, srcl);
            float ev = __shfl(evl, srcl);   // ev==0 for invalid edges
            if (ld) {
                const float4* pc = (const float4*)(Pb + o4);
                float4 v = pc[sub4];
                a4.x = fmaf(ev, v.x, a4.x);
                a4.y = fmaf(ev, v.y, a4.y);
                a4.z = fmaf(ev, v.z, a4.z);   // sub4==12: v.z == P[50] == 1 -> ssum
                a4.w = fmaf(ev, v.w, a4.w);
            }
        }
    }
    #pragma unroll
    for (int off = 32; off >= 16; off >>= 1) {
        a4.x += __shfl_xor(a4.x, off);
        a4.y += __shfl_xor(a4.y, off);
        a4.z += __shfl_xor(a4.z, off);
        a4.w += __shfl_xor(a4.w, off);
    }
    // ssum = full-row sum of ev: lane 12's a4.z after the reduce (element 50)
    float ssum = __shfl(a4.z, 12);

    int src = lane >> 2;
    float fx = __shfl(a4.x, src), fy = __shfl(a4.y, src);
    float fz = __shfl(a4.z, src), fw = __shfl(a4.w, src);
    float za = (lane & 1) ? ((lane & 2) ? fw : fy) : ((lane & 2) ? fz : fx);

    float inv = (ssum > 0.f) ? (1.f / ssum) : 0.f;
    float zl = act ? leakyf(za * inv) : 0.f;

    // epilogue matvec via LDS broadcast reads (scalar o per lane, no arrays)
    if (act) zsh[wslot][lane] = zl;
    int fcol = act ? ((lane < DK) ? lane : (lane - DK)) : 0;
    int kbase = (act && lane >= DK) ? DK : 0;
    float o = 0.f;
    #pragma unroll
    for (int d = 0; d < DK; ++d)
        o = fmaf(zsh[wslot][kbase + d], Wsh[d * DK + fcol], o);

    float th = act ? fast_tanhf(o) * qv[fcol] : 0.f;
    float t0 = (lane < DK) ? th : 0.f;
    float t1 = th - t0;
    #pragma unroll
    for (int off = 32; off; off >>= 1) { t0 += __shfl_xor(t0, off); t1 += __shfl_xor(t1, off); }
    float m = fmaxf(t0, t1);
    float e0 = __expf(t0 - m), e1 = __expf(t1 - m);
    float rinv = 1.f / (e0 + e1);

    if (act) A.z[rel][(size_t)u * PS + lane] = o;
    if (lane == 0) {
        A.r[rel][(size_t)u * 2 + 0] = e0 * rinv;
        A.r[rel][(size_t)u * 2 + 1] = e1 * rinv;
    }
}

// ---------------- ego (float4 z loads + fused out + fused scores) ----------------
struct EgoArgs {
    float* P0; float* P1;
    const float* zz[8];   // PS stride
    const float* rr[8];
    const float* at;      // [8][2][50]
    float2* sa[8]; float2* sb0; float2* sb1;
    float* outp;          // non-null on last iteration (P write + scores skipped)
    int n0, n1;
};

__global__ __launch_bounds__(256) void ego_kernel(EgoArgs A) {
    int g = blockIdx.x * blockDim.x + threadIdx.x;
    if (g >= A.n0 + A.n1) return;
    float acc[DD];
    bool is0 = g < A.n0;
    int node = is0 ? g : g - A.n0;
    float* Pr = (is0 ? A.P0 : A.P1) + (size_t)node * PS;
    {
        const float4* p4 = (const float4*)Pr;
        #pragma unroll
        for (int t = 0; t < 12; ++t) {
            float4 v = p4[t];
            acc[4 * t] = v.x; acc[4 * t + 1] = v.y; acc[4 * t + 2] = v.z; acc[4 * t + 3] = v.w;
        }
        acc[48] = Pr[48]; acc[49] = Pr[49];
    }
    int jbeg = is0 ? 0 : 1, jend = is0 ? 1 : 8;
    #pragma unroll 1
    for (int j = jbeg; j < jend; ++j) {
        const float* zr = A.zz[j] + (size_t)node * PS;
        float r0 = A.rr[j][(size_t)node * 2], r1 = A.rr[j][(size_t)node * 2 + 1];
        const float4* z4 = (const float4*)zr;
        #pragma unroll
        for (int t = 0; t < 12; ++t) {
            float4 v = z4[t];
            acc[4 * t]     = fmaf(v.x, (4 * t     < DK) ? r0 : r1, acc[4 * t]);
            acc[4 * t + 1] = fmaf(v.y, (4 * t + 1 < DK) ? r0 : r1, acc[4 * t + 1]);
            acc[4 * t + 2] = fmaf(v.z, (4 * t + 2 < DK) ? r0 : r1, acc[4 * t + 2]);
            acc[4 * t + 3] = fmaf(v.w, (4 * t + 3 < DK) ? r0 : r1, acc[4 * t + 3]);
        }
        acc[48] = fmaf(zr[48], r1, acc[48]);
        acc[49] = fmaf(zr[49], r1, acc[49]);
    }
    // l2norm per factor
    #pragma unroll
    for (int k = 0; k < KF; ++k) {
        float nrm = 0.f;
        #pragma unroll
        for (int f = 0; f < DK; ++f) nrm = fmaf(acc[k * DK + f], acc[k * DK + f], nrm);
        float inv = 1.f / fmaxf(sqrtf(nrm), 1e-12f);
        #pragma unroll
        for (int f = 0; f < DK; ++f) acc[k * DK + f] *= inv;
    }

    if (A.outp) {
        // last iteration: P is dead afterwards; write only the output row
        float* dst = A.outp + (size_t)g * DD;
        #pragma unroll
        for (int f = 0; f < DD; ++f) dst[f] = acc[f];
        return;
    }

    #pragma unroll
    for (int f = 0; f < DD; ++f) Pr[f] = acc[f];
    // P[50] stays 1.0 from fac (ssum pad), P[51] stays 0.

    // scores from the new P row (registers)
    if (is0) {
        A.sa[0][node] = score_row50(acc, A.at + 0);
        A.sb1[node]   = score_col50(acc, A.at + 100);
    } else {
        #pragma unroll 1
        for (int e = 1; e < 8; ++e) A.sa[e][node] = score_row50(acc, A.at + e * 100);
        A.sb0[node] = score_col50(acc, A.at + 0);
    }
}

static inline int cdiv(int a, int b) { return (a + b - 1) / b; }

extern "C" void kernel_launch(void* const* d_in, const int* in_sizes, int n_in,
                              void* d_out, int out_size, void* d_ws, size_t ws_size,
                              hipStream_t stream) {
    const int* edge[8];
    int E[8];
    for (int e = 0; e < 8; ++e) { edge[e] = (const int*)d_in[e]; E[e] = in_sizes[e] / 2; }
    const float* emb[8];
    int nn[8];
    for (int i = 0; i < 8; ++i) { emb[i] = (const float*)d_in[8 + i]; nn[i] = in_sizes[8 + i] / DD; }
    const float* Wtk = (const float*)d_in[16];
    const float* at  = (const float*)d_in[17];
    const float* W   = (const float*)d_in[18];
    const float* q   = (const float*)d_in[19];
    float* out = (float*)d_out;

    static const int aIdx[8] = {0, 1, 1, 1, 1, 1, 1, 1};
    static const int bIdx[8] = {1, 0, 2, 3, 4, 5, 6, 7};
    int rows[8], ncol[8];
    for (int e = 0; e < 8; ++e) { rows[e] = nn[aIdx[e]]; ncol[e] = nn[bIdx[e]]; }
    int rowbase[9];
    rowbase[0] = 0;
    for (int e = 0; e < 8; ++e) rowbase[e + 1] = rowbase[e] + rows[e];
    int totalRows = rowbase[8];
    int ebase[9];
    ebase[0] = 0;
    for (int e = 0; e < 8; ++e) ebase[e + 1] = ebase[e] + E[e];
    int totE = ebase[8];

    // ---- workspace: P(52), z(52), r, sb, sa, cnt(+1), bsum, rank, colind ----
    char* w = (char*)d_ws;
    size_t off = 0;
    auto alloc_f  = [&](size_t n) { float*  p = (float*)(w + off);  off += n * 4; return p; };
    auto alloc_f2 = [&](size_t n) { float2* p = (float2*)(w + off); off += n * 8; return p; };
    auto alloc_i  = [&](size_t n) { int*    p = (int*)(w + off);    off += n * 4; return p; };
    float* P[8]; for (int i = 0; i < 8; ++i) P[i] = alloc_f((size_t)nn[i] * PS);
    float* z[8]; for (int e = 0; e < 8; ++e) z[e] = alloc_f((size_t)rows[e] * PS);
    float* r[8]; for (int e = 0; e < 8; ++e) r[e] = alloc_f((size_t)rows[e] * 2);
    float2* sb[8]; for (int e = 0; e < 8; ++e) sb[e] = alloc_f2((size_t)ncol[e]);
    float2* sa[8]; for (int e = 0; e < 8; ++e) sa[e] = alloc_f2((size_t)rows[e]);
    int nScan = totalRows + 1;
    int* cnt = alloc_i((size_t)nScan);
    int nchunks = cdiv(nScan, 1024);
    int* bsum = alloc_i((size_t)nchunks);
    unsigned* rank = (unsigned*)alloc_i((size_t)totE);
    unsigned short* colind = (unsigned short*)(w + off);
    off += (size_t)totE * 2;
    (void)ws_size;

    const int B = 256;

    // ---- flat CSR build (single atomic pass) ----
    hipMemsetAsync(cnt, 0, (size_t)nScan * 4, stream);
    EdgeArgs EA;
    for (int e = 0; e < 8; ++e) {
        EA.rows[e] = edge[e]; EA.cols[e] = edge[e] + E[e];
        EA.rowbase[e] = rowbase[e];
        EA.ebase[e] = ebase[e];
    }
    EA.ebase[8] = ebase[8];
    EA.cnt = cnt; EA.rank = rank; EA.colind = colind;
    rank_kernel<<<cdiv(totE, B), B, 0, stream>>>(EA);
    scan_part_kernel<<<nchunks, 1024, 0, stream>>>(cnt, nScan, bsum);
    scan_bsum_kernel<<<1, 1024, 0, stream>>>(bsum, nchunks);
    add_off_kernel<<<nchunks, 1024, 0, stream>>>(cnt, nScan, bsum);
    place_kernel<<<cdiv(totE, B), B, 0, stream>>>(EA);  // cnt untouched: exclusive starts

    // ---- fac ----
    FacArgs FA;
    FA.base[0] = 0;
    for (int i = 0; i < 8; ++i) { FA.emb[i] = emb[i]; FA.P[i] = P[i]; FA.base[i + 1] = FA.base[i] + nn[i]; }
    FA.Wtk = Wtk;
    fac_kernel<<<cdiv(FA.base[8], B), B, 0, stream>>>(FA);

    // ---- static sb (rels 2..7) once ----
    SbArgs SBs;
    SBs.base[0] = 0;
    for (int e = 2; e < 8; ++e) {
        SBs.Pb[e - 2] = P[bIdx[e]];
        SBs.at[e - 2] = at + (size_t)e * KF * DD;
        SBs.sb[e - 2] = sb[e];
        SBs.base[e - 1] = SBs.base[e - 2] + ncol[e];
    }
    sb_kernel<<<cdiv(SBs.base[6], B), B, 0, stream>>>(SBs);

    // ---- initial dynamic scores (sa all rels + sb0/sb1) ----
    ScoreArgs SC;
    SC.P0 = P[0]; SC.P1 = P[1]; SC.at = at;
    for (int e = 0; e < 8; ++e) SC.sa[e] = sa[e];
    SC.sb0 = sb[0]; SC.sb1 = sb[1];
    SC.n0 = nn[0]; SC.n1 = nn[1];
    score01_kernel<<<cdiv(nn[0] + nn[1], B), B, 0, stream>>>(SC);

    // ---- iterations ----
    PhaseArgs PA;
    PA.rowptr = cnt; PA.colind = colind;
    for (int e = 0; e < 8; ++e) {
        PA.Pb[e] = P[bIdx[e]];
        PA.q[e]  = q + (size_t)e * DK;
        PA.sa[e] = sa[e]; PA.sb[e] = sb[e];
        PA.z[e] = z[e]; PA.r[e] = r[e];
        PA.rowbase[e] = rowbase[e];
    }
    PA.rowbase[8] = rowbase[8];
    PA.W = W;
    EgoArgs GA;
    GA.P0 = P[0]; GA.P1 = P[1]; GA.n0 = nn[0]; GA.n1 = nn[1];
    for (int e = 0; e < 8; ++e) { GA.zz[e] = z[e]; GA.rr[e] = r[e]; GA.sa[e] = sa[e]; }
    GA.at = at;
    GA.sb0 = sb[0]; GA.sb1 = sb[1];
    GA.outp = nullptr;

    for (int it = 0; it < ITERS; ++it) {
        phase_kernel<<<cdiv(totalRows, WPB), WPB * 64, 0, stream>>>(PA, totalRows);
        GA.outp = (it == ITERS - 1) ? out : nullptr;
        ego_kernel<<<cdiv(nn[0] + nn[1], B), B, 0, stream>>>(GA);
    }
}

// Round 15
// 1427.924 us; speedup vs baseline: 1.0504x; 1.0504x over previous
//
#include <hip/hip_runtime.h>
#include <math.h>

// GraphEncoder v21 = v20 minus the NT store (single reversion).
// v20 A/B result: pad-ssum phase 240.6->235.3us (KEEP); NT u16 store in
// place cost ~+77us non-phase (write-through per 2B defeats L2 write
// combining; REJECTED permanently). place reverts to the plain store that
// measured ~90us in v16/v19.
// Current composition (all measured-good): pad-ssum phase + LDS-broadcast
// epilogue + sub4<13 mask + offset-shuffle t-loop; single-atomic CSR
// (rank/scan/place); ego with fused scores + fused out + dead-P-skip.

#define KF 2
#define DK 25
#define DD 50
#define PS 52   // padded P/z row stride: 208 B = 13 float4
#define ITERS 4
#define WPB 4

static __device__ __forceinline__ float leakyf(float x) { return x > 0.f ? x : 0.2f * x; }

static __device__ __forceinline__ float fast_tanhf(float x) {
    float e = __expf(2.f * x);
    return 1.f - 2.f * __builtin_amdgcn_rcpf(e + 1.f);
}

// at[e] is [2][50]: factor k at a+k*50; 0..24 row-side, 25..49 col-side.
static __device__ __forceinline__ float2 score_row50(const float* p, const float* a) {
    float s0 = 0.f, s1 = 0.f;
    #pragma unroll
    for (int f = 0; f < DK; ++f) {
        s0 = fmaf(p[f],      a[f],      s0);
        s1 = fmaf(p[DK + f], a[50 + f], s1);
    }
    return make_float2(s0, s1);
}
static __device__ __forceinline__ float2 score_col50(const float* p, const float* a) {
    float s0 = 0.f, s1 = 0.f;
    #pragma unroll
    for (int f = 0; f < DK; ++f) {
        s0 = fmaf(p[f],      a[25 + f], s0);
        s1 = fmaf(p[DK + f], a[75 + f], s1);
    }
    return make_float2(s0, s1);
}

// ---------------- fac ----------------
struct FacArgs { const float* emb[8]; float* P[8]; const float* Wtk; int base[9]; };

__global__ void fac_kernel(FacArgs A) {
    int g = blockIdx.x * blockDim.x + threadIdx.x;
    if (g >= A.base[8]) return;
    int ty = 0;
    while (g >= A.base[ty + 1]) ++ty;
    int node = g - A.base[ty];
    const float* er = A.emb[ty] + (size_t)node * DD;
    const float* Wt = A.Wtk + (size_t)ty * KF * DD * DK;
    float x[DD];
    #pragma unroll
    for (int d = 0; d < DD; ++d) x[d] = er[d];
    float out[DD];
    #pragma unroll
    for (int k = 0; k < KF; ++k) {
        const float* Wk = Wt + k * DD * DK;
        float nrm = 0.f;
        for (int f = 0; f < DK; ++f) {
            float acc = 0.f;
            for (int d = 0; d < DD; ++d) acc = fmaf(x[d], Wk[d * DK + f], acc);
            acc = leakyf(acc);
            out[k * DK + f] = acc;
            nrm = fmaf(acc, acc, nrm);
        }
        float inv = 1.f / fmaxf(sqrtf(nrm), 1e-12f);
        for (int f = 0; f < DK; ++f) out[k * DK + f] *= inv;
    }
    float* Pr = A.P[ty] + (size_t)node * PS;
    #pragma unroll
    for (int j = 0; j < DD; ++j) Pr[j] = out[j];
    Pr[50] = 1.f;   // ssum pad column: gather accumulates ev*1 into a4.z
    Pr[51] = 0.f;
}

// ---------------- flat CSR build (single atomic pass) ----------------
struct EdgeArgs {
    const int* rows[8]; const int* cols[8];
    int* cnt;                  // [totalRows+1] counts -> exclusive starts
    unsigned* rank;            // [totE] within-row rank
    unsigned short* colind;    // [totE] flat
    int ebase[9];
    int rowbase[8];
};

__global__ void rank_kernel(EdgeArgs A) {
    int g = blockIdx.x * blockDim.x + threadIdx.x;
    if (g >= A.ebase[8]) return;
    int rel = 0;
    while (g >= A.ebase[rel + 1]) ++rel;
    int e = g - A.ebase[rel];
    A.rank[g] = (unsigned)atomicAdd(&A.cnt[A.rowbase[rel] + A.rows[rel][e]], 1);
}

// 3-kernel hierarchical exclusive scan over cnt[0..n)
__global__ __launch_bounds__(1024) void scan_part_kernel(int* a, int n, int* bsum) {
    __shared__ int lds[1024];
    int tid = threadIdx.x;
    int i = blockIdx.x * 1024 + tid;
    int v = (i < n) ? a[i] : 0;
    lds[tid] = v;
    __syncthreads();
    int x = v;
    for (int off = 1; off < 1024; off <<= 1) {
        int y = (tid >= off) ? lds[tid - off] : 0;
        __syncthreads();
        x += y;
        lds[tid] = x;
        __syncthreads();
    }
    if (i < n) a[i] = x - v;              // exclusive within chunk
    if (tid == 1023) bsum[blockIdx.x] = x; // chunk total
}

__global__ __launch_bounds__(1024) void scan_bsum_kernel(int* bsum, int nb) {
    __shared__ int lds[1024];
    int tid = threadIdx.x;
    int v = (tid < nb) ? bsum[tid] : 0;
    lds[tid] = v;
    __syncthreads();
    int x = v;
    for (int off = 1; off < 1024; off <<= 1) {
        int y = (tid >= off) ? lds[tid - off] : 0;
        __syncthreads();
        x += y;
        lds[tid] = x;
        __syncthreads();
    }
    if (tid < nb) bsum[tid] = x - v;      // exclusive chunk offsets
}

__global__ __launch_bounds__(1024) void add_off_kernel(int* a, int n, const int* bsum) {
    int i = blockIdx.x * 1024 + threadIdx.x;
    if (i < n) a[i] += bsum[blockIdx.x];
}

// place: no atomics; p = start[grow] + rank[e]  (plain store — NT measured worse)
__global__ void place_kernel(EdgeArgs A) {
    int g = blockIdx.x * blockDim.x + threadIdx.x;
    if (g >= A.ebase[8]) return;
    int rel = 0;
    while (g >= A.ebase[rel + 1]) ++rel;
    int e = g - A.ebase[rel];
    int p = A.cnt[A.rowbase[rel] + A.rows[rel][e]] + (int)A.rank[g];
    A.colind[p] = (unsigned short)A.cols[rel][e];
}

// ---------------- sb init for static relations 2..7 ----------------
struct SbArgs { const float* Pb[6]; const float* at[6]; float2* sb[6]; int base[7]; };

__global__ void sb_kernel(SbArgs A) {
    int g = blockIdx.x * blockDim.x + threadIdx.x;
    if (g >= A.base[6]) return;
    int rel = 0;
    while (g >= A.base[rel + 1]) ++rel;
    int c = g - A.base[rel];
    const float* p = A.Pb[rel] + (size_t)c * PS;
    A.sb[rel][c] = score_col50(p, A.at[rel]);
}

// ---------------- score01: INITIAL sa (all rels) + sb0/sb1 (after fac) ----------------
struct ScoreArgs {
    const float* P0; const float* P1;
    const float* at;
    float2* sa[8]; float2* sb0; float2* sb1;
    int n0, n1;
};

__global__ void score01_kernel(ScoreArgs A) {
    int g = blockIdx.x * blockDim.x + threadIdx.x;
    if (g >= A.n0 + A.n1) return;
    if (g < A.n0) {
        const float* p = A.P0 + (size_t)g * PS;
        float pr[DD];
        #pragma unroll
        for (int j = 0; j < DD; ++j) pr[j] = p[j];
        A.sa[0][g] = score_row50(pr, A.at + 0);
        A.sb1[g]   = score_col50(pr, A.at + 100);
    } else {
        int node = g - A.n0;
        const float* p = A.P1 + (size_t)node * PS;
        float pr[DD];
        #pragma unroll
        for (int j = 0; j < DD; ++j) pr[j] = p[j];
        #pragma unroll
        for (int e = 1; e < 8; ++e) A.sa[e][node] = score_row50(pr, A.at + e * 100);
        A.sb0[node] = score_col50(pr, A.at + 0);
    }
}

// ---------------- fused phase (gather + LDS epilogue; ssum via pad) ----------------
struct PhaseArgs {
    const int* rowptr;               // [totalRows+1] exclusive starts (flat)
    const unsigned short* colind;    // flat
    const float* Pb[8];
    const float* q[8];
    const float2* sa[8]; const float2* sb[8];
    float* z[8]; float* r[8];
    const float* W;
    int rowbase[9];
};

__global__ __launch_bounds__(WPB * 64) void phase_kernel(PhaseArgs A, int totalRows) {
    __shared__ float Wsh[DK * DK];
    __shared__ float zsh[WPB][DD];
    for (int i = threadIdx.x; i < DK * DK; i += WPB * 64) Wsh[i] = A.W[i];
    __syncthreads();

    int wslot = threadIdx.x >> 6;
    int wave = blockIdx.x * WPB + wslot;
    int lane = threadIdx.x & 63;
    if (wave >= totalRows) return;
    int rel = 0;
    while (wave >= A.rowbase[rel + 1]) ++rel;
    int u = wave - A.rowbase[rel];

    const unsigned short* colind = A.colind;
    const char* Pb = (const char*)A.Pb[rel];
    const float* qv = A.q[rel];
    const float2* sb = A.sb[rel];
    float2 h = A.sa[rel][u];
    int beg = A.rowptr[wave];
    int end = A.rowptr[wave + 1];

    bool act = lane < DD;
    int grp4 = lane >> 4, sub4 = lane & 15;
    bool ld = sub4 < 13;   // P row is 13 float4; element 50 is the ssum pad
    float4 a4 = make_float4(0.f, 0.f, 0.f, 0.f);

    for (int base = beg; base < end; base += 64) {
        int idx = base + lane;
        bool vld = idx < end;
        int cb = vld ? (int)colind[idx] : 0;
        unsigned ob = (unsigned)cb * (unsigned)(PS * 4);   // byte offset, 64-wide
        float evl = 0.f;
        if (vld) {
            float2 sc = sb[cb];
            evl = __expf(0.5f * (fmaxf(h.x + sc.x, 0.f) + fmaxf(h.y + sc.y, 0.f)));
        }
        int nb = min(64, end - base);
        #pragma unroll 4
        for (int t = 0; t < nb; t += 4) {
            int srcl = t + grp4;
            unsigned o4 = __shfl(ob, srcl);
            float ev = __shfl(evl, srcl);   // ev==0 for invalid edges
            if (ld) {
                const float4* pc = (const float4*)(Pb + o4);
                float4 v = pc[sub4];
                a4.x = fmaf(ev, v.x, a4.x);
                a4.y = fmaf(ev, v.y, a4.y);
                a4.z = fmaf(ev, v.z, a4.z);   // sub4==12: v.z == P[50] == 1 -> ssum
                a4.w = fmaf(ev, v.w, a4.w);
            }
        }
    }
    #pragma unroll
    for (int off = 32; off >= 16; off >>= 1) {
        a4.x += __shfl_xor(a4.x, off);
        a4.y += __shfl_xor(a4.y, off);
        a4.z += __shfl_xor(a4.z, off);
        a4.w += __shfl_xor(a4.w, off);
    }
    // ssum = full-row sum of ev: lane 12's a4.z after the reduce (element 50)
    float ssum = __shfl(a4.z, 12);

    int src = lane >> 2;
    float fx = __shfl(a4.x, src), fy = __shfl(a4.y, src);
    float fz = __shfl(a4.z, src), fw = __shfl(a4.w, src);
    float za = (lane & 1) ? ((lane & 2) ? fw : fy) : ((lane & 2) ? fz : fx);

    float inv = (ssum > 0.f) ? (1.f / ssum) : 0.f;
    float zl = act ? leakyf(za * inv) : 0.f;

    // epilogue matvec via LDS broadcast reads (scalar o per lane, no arrays)
    if (act) zsh[wslot][lane] = zl;
    int fcol = act ? ((lane < DK) ? lane : (lane - DK)) : 0;
    int kbase = (act && lane >= DK) ? DK : 0;
    float o = 0.f;
    #pragma unroll
    for (int d = 0; d < DK; ++d)
        o = fmaf(zsh[wslot][kbase + d], Wsh[d * DK + fcol], o);

    float th = act ? fast_tanhf(o) * qv[fcol] : 0.f;
    float t0 = (lane < DK) ? th : 0.f;
    float t1 = th - t0;
    #pragma unroll
    for (int off = 32; off; off >>= 1) { t0 += __shfl_xor(t0, off); t1 += __shfl_xor(t1, off); }
    float m = fmaxf(t0, t1);
    float e0 = __expf(t0 - m), e1 = __expf(t1 - m);
    float rinv = 1.f / (e0 + e1);

    if (act) A.z[rel][(size_t)u * PS + lane] = o;
    if (lane == 0) {
        A.r[rel][(size_t)u * 2 + 0] = e0 * rinv;
        A.r[rel][(size_t)u * 2 + 1] = e1 * rinv;
    }
}

// ---------------- ego (float4 z loads + fused out + fused scores) ----------------
struct EgoArgs {
    float* P0; float* P1;
    const float* zz[8];   // PS stride
    const float* rr[8];
    const float* at;      // [8][2][50]
    float2* sa[8]; float2* sb0; float2* sb1;
    float* outp;          // non-null on last iteration (P write + scores skipped)
    int n0, n1;
};

__global__ __launch_bounds__(256) void ego_kernel(EgoArgs A) {
    int g = blockIdx.x * blockDim.x + threadIdx.x;
    if (g >= A.n0 + A.n1) return;
    float acc[DD];
    bool is0 = g < A.n0;
    int node = is0 ? g : g - A.n0;
    float* Pr = (is0 ? A.P0 : A.P1) + (size_t)node * PS;
    {
        const float4* p4 = (const float4*)Pr;
        #pragma unroll
        for (int t = 0; t < 12; ++t) {
            float4 v = p4[t];
            acc[4 * t] = v.x; acc[4 * t + 1] = v.y; acc[4 * t + 2] = v.z; acc[4 * t + 3] = v.w;
        }
        acc[48] = Pr[48]; acc[49] = Pr[49];
    }
    int jbeg = is0 ? 0 : 1, jend = is0 ? 1 : 8;
    #pragma unroll 1
    for (int j = jbeg; j < jend; ++j) {
        const float* zr = A.zz[j] + (size_t)node * PS;
        float r0 = A.rr[j][(size_t)node * 2], r1 = A.rr[j][(size_t)node * 2 + 1];
        const float4* z4 = (const float4*)zr;
        #pragma unroll
        for (int t = 0; t < 12; ++t) {
            float4 v = z4[t];
            acc[4 * t]     = fmaf(v.x, (4 * t     < DK) ? r0 : r1, acc[4 * t]);
            acc[4 * t + 1] = fmaf(v.y, (4 * t + 1 < DK) ? r0 : r1, acc[4 * t + 1]);
            acc[4 * t + 2] = fmaf(v.z, (4 * t + 2 < DK) ? r0 : r1, acc[4 * t + 2]);
            acc[4 * t + 3] = fmaf(v.w, (4 * t + 3 < DK) ? r0 : r1, acc[4 * t + 3]);
        }
        acc[48] = fmaf(zr[48], r1, acc[48]);
        acc[49] = fmaf(zr[49], r1, acc[49]);
    }
    // l2norm per factor
    #pragma unroll
    for (int k = 0; k < KF; ++k) {
        float nrm = 0.f;
        #pragma unroll
        for (int f = 0; f < DK; ++f) nrm = fmaf(acc[k * DK + f], acc[k * DK + f], nrm);
        float inv = 1.f / fmaxf(sqrtf(nrm), 1e-12f);
        #pragma unroll
        for (int f = 0; f < DK; ++f) acc[k * DK + f] *= inv;
    }

    if (A.outp) {
        // last iteration: P is dead afterwards; write only the output row
        float* dst = A.outp + (size_t)g * DD;
        #pragma unroll
        for (int f = 0; f < DD; ++f) dst[f] = acc[f];
        return;
    }

    #pragma unroll
    for (int f = 0; f < DD; ++f) Pr[f] = acc[f];
    // P[50] stays 1.0 from fac (ssum pad), P[51] stays 0.

    // scores from the new P row (registers)
    if (is0) {
        A.sa[0][node] = score_row50(acc, A.at + 0);
        A.sb1[node]   = score_col50(acc, A.at + 100);
    } else {
        #pragma unroll 1
        for (int e = 1; e < 8; ++e) A.sa[e][node] = score_row50(acc, A.at + e * 100);
        A.sb0[node] = score_col50(acc, A.at + 0);
    }
}

static inline int cdiv(int a, int b) { return (a + b - 1) / b; }

extern "C" void kernel_launch(void* const* d_in, const int* in_sizes, int n_in,
                              void* d_out, int out_size, void* d_ws, size_t ws_size,
                              hipStream_t stream) {
    const int* edge[8];
    int E[8];
    for (int e = 0; e < 8; ++e) { edge[e] = (const int*)d_in[e]; E[e] = in_sizes[e] / 2; }
    const float* emb[8];
    int nn[8];
    for (int i = 0; i < 8; ++i) { emb[i] = (const float*)d_in[8 + i]; nn[i] = in_sizes[8 + i] / DD; }
    const float* Wtk = (const float*)d_in[16];
    const float* at  = (const float*)d_in[17];
    const float* W   = (const float*)d_in[18];
    const float* q   = (const float*)d_in[19];
    float* out = (float*)d_out;

    static const int aIdx[8] = {0, 1, 1, 1, 1, 1, 1, 1};
    static const int bIdx[8] = {1, 0, 2, 3, 4, 5, 6, 7};
    int rows[8], ncol[8];
    for (int e = 0; e < 8; ++e) { rows[e] = nn[aIdx[e]]; ncol[e] = nn[bIdx[e]]; }
    int rowbase[9];
    rowbase[0] = 0;
    for (int e = 0; e < 8; ++e) rowbase[e + 1] = rowbase[e] + rows[e];
    int totalRows = rowbase[8];
    int ebase[9];
    ebase[0] = 0;
    for (int e = 0; e < 8; ++e) ebase[e + 1] = ebase[e] + E[e];
    int totE = ebase[8];

    // ---- workspace: P(52), z(52), r, sb, sa, cnt(+1), bsum, rank, colind ----
    char* w = (char*)d_ws;
    size_t off = 0;
    auto alloc_f  = [&](size_t n) { float*  p = (float*)(w + off);  off += n * 4; return p; };
    auto alloc_f2 = [&](size_t n) { float2* p = (float2*)(w + off); off += n * 8; return p; };
    auto alloc_i  = [&](size_t n) { int*    p = (int*)(w + off);    off += n * 4; return p; };
    float* P[8]; for (int i = 0; i < 8; ++i) P[i] = alloc_f((size_t)nn[i] * PS);
    float* z[8]; for (int e = 0; e < 8; ++e) z[e] = alloc_f((size_t)rows[e] * PS);
    float* r[8]; for (int e = 0; e < 8; ++e) r[e] = alloc_f((size_t)rows[e] * 2);
    float2* sb[8]; for (int e = 0; e < 8; ++e) sb[e] = alloc_f2((size_t)ncol[e]);
    float2* sa[8]; for (int e = 0; e < 8; ++e) sa[e] = alloc_f2((size_t)rows[e]);
    int nScan = totalRows + 1;
    int* cnt = alloc_i((size_t)nScan);
    int nchunks = cdiv(nScan, 1024);
    int* bsum = alloc_i((size_t)nchunks);
    unsigned* rank = (unsigned*)alloc_i((size_t)totE);
    unsigned short* colind = (unsigned short*)(w + off);
    off += (size_t)totE * 2;
    (void)ws_size;

    const int B = 256;

    // ---- flat CSR build (single atomic pass) ----
    hipMemsetAsync(cnt, 0, (size_t)nScan * 4, stream);
    EdgeArgs EA;
    for (int e = 0; e < 8; ++e) {
        EA.rows[e] = edge[e]; EA.cols[e] = edge[e] + E[e];
        EA.rowbase[e] = rowbase[e];
        EA.ebase[e] = ebase[e];
    }
    EA.ebase[8] = ebase[8];
    EA.cnt = cnt; EA.rank = rank; EA.colind = colind;
    rank_kernel<<<cdiv(totE, B), B, 0, stream>>>(EA);
    scan_part_kernel<<<nchunks, 1024, 0, stream>>>(cnt, nScan, bsum);
    scan_bsum_kernel<<<1, 1024, 0, stream>>>(bsum, nchunks);
    add_off_kernel<<<nchunks, 1024, 0, stream>>>(cnt, nScan, bsum);
    place_kernel<<<cdiv(totE, B), B, 0, stream>>>(EA);  // cnt untouched: exclusive starts

    // ---- fac ----
    FacArgs FA;
    FA.base[0] = 0;
    for (int i = 0; i < 8; ++i) { FA.emb[i] = emb[i]; FA.P[i] = P[i]; FA.base[i + 1] = FA.base[i] + nn[i]; }
    FA.Wtk = Wtk;
    fac_kernel<<<cdiv(FA.base[8], B), B, 0, stream>>>(FA);

    // ---- static sb (rels 2..7) once ----
    SbArgs SBs;
    SBs.base[0] = 0;
    for (int e = 2; e < 8; ++e) {
        SBs.Pb[e - 2] = P[bIdx[e]];
        SBs.at[e - 2] = at + (size_t)e * KF * DD;
        SBs.sb[e - 2] = sb[e];
        SBs.base[e - 1] = SBs.base[e - 2] + ncol[e];
    }
    sb_kernel<<<cdiv(SBs.base[6], B), B, 0, stream>>>(SBs);

    // ---- initial dynamic scores (sa all rels + sb0/sb1) ----
    ScoreArgs SC;
    SC.P0 = P[0]; SC.P1 = P[1]; SC.at = at;
    for (int e = 0; e < 8; ++e) SC.sa[e] = sa[e];
    SC.sb0 = sb[0]; SC.sb1 = sb[1];
    SC.n0 = nn[0]; SC.n1 = nn[1];
    score01_kernel<<<cdiv(nn[0] + nn[1], B), B, 0, stream>>>(SC);

    // ---- iterations ----
    PhaseArgs PA;
    PA.rowptr = cnt; PA.colind = colind;
    for (int e = 0; e < 8; ++e) {
        PA.Pb[e] = P[bIdx[e]];
        PA.q[e]  = q + (size_t)e * DK;
        PA.sa[e] = sa[e]; PA.sb[e] = sb[e];
        PA.z[e] = z[e]; PA.r[e] = r[e];
        PA.rowbase[e] = rowbase[e];
    }
    PA.rowbase[8] = rowbase[8];
    PA.W = W;
    EgoArgs GA;
    GA.P0 = P[0]; GA.P1 = P[1]; GA.n0 = nn[0]; GA.n1 = nn[1];
    for (int e = 0; e < 8; ++e) { GA.zz[e] = z[e]; GA.rr[e] = r[e]; GA.sa[e] = sa[e]; }
    GA.at = at;
    GA.sb0 = sb[0]; GA.sb1 = sb[1];
    GA.outp = nullptr;

    for (int it = 0; it < ITERS; ++it) {
        phase_kernel<<<cdiv(totalRows, WPB), WPB * 64, 0, stream>>>(PA, totalRows);
        GA.outp = (it == ITERS - 1) ? out : nullptr;
        ego_kernel<<<cdiv(nn[0] + nn[1], B), B, 0, stream>>>(GA);
    }
}